// Round 14
// baseline (249.963 us; speedup 1.0000x reference)
//
#include <hip/hip_runtime.h>
#include <cstdint>
#include <cmath>

#define D 256
#define NEG 0.2f

typedef __attribute__((ext_vector_type(8))) __bf16 bf16x8;
typedef __attribute__((ext_vector_type(8))) unsigned short ushort8;
typedef __attribute__((ext_vector_type(4))) float f32x4;

__device__ __forceinline__ unsigned short f2bf(float f){
    unsigned u = __float_as_uint(f);
    return (unsigned short)((u + 0x7fffu + ((u >> 16) & 1u)) >> 16);  // RNE
}
__device__ __forceinline__ float b2f(unsigned short u){
    return __uint_as_float(((unsigned)u) << 16);
}

// ---- prep W: WT[col][k] = bf16(W[k][col]) (linear, transposed); biascat ----
__global__ __launch_bounds__(256) void prep_w_kernel(
    const float* __restrict__ Wsrc, const float* __restrict__ Wdst,
    const float* __restrict__ bsrc, const float* __restrict__ bdst,
    unsigned short* __restrict__ WT, float* __restrict__ biascat)
{
    int idx = blockIdx.x*256 + threadIdx.x;     // 512 cols * 32 units = 16384
    int col = idx >> 5;
    int u   = idx & 31;
    const float* W = (col < 256) ? Wsrc : Wdst;
    int c = col & 255;
    ushort8 o;
    #pragma unroll
    for (int j = 0; j < 8; ++j)
        o[j] = f2bf(W[(size_t)(u*8 + j)*D + c]);
    *(ushort8*)(WT + (size_t)col*D + u*8) = o;
    if (idx < 512) biascat[idx] = (idx < 256) ? bsrc[idx] : bdst[idx-256];
}

// ---- prep feat: featb = bf16(feat), linear, zero-padded to NPAD rows ----
__global__ __launch_bounds__(256) void prep_feat_kernel(
    const float* __restrict__ feat, unsigned short* __restrict__ featb, int N, int NPAD)
{
    int total = NPAD * 32;   // 16B units
    for (int idx = blockIdx.x*256 + threadIdx.x; idx < total; idx += gridDim.x*256){
        int r = idx >> 5;
        int u = idx & 31;
        ushort8 o;
        if (r < N){
            const float* s = feat + (size_t)r*D + u*8;
            float4 a = *(const float4*)s;
            float4 b = *(const float4*)(s + 4);
            o[0]=f2bf(a.x); o[1]=f2bf(a.y); o[2]=f2bf(a.z); o[3]=f2bf(a.w);
            o[4]=f2bf(b.x); o[5]=f2bf(b.y); o[6]=f2bf(b.z); o[7]=f2bf(b.w);
        } else {
            #pragma unroll
            for (int j = 0; j < 8; ++j) o[j] = 0;
        }
        *(ushort8*)(featb + (size_t)r*D + u*8) = o;
    }
}

// ---- bf16 MFMA projection, NO LDS / NO BARRIERS: fragments loaded directly from
// L2 (featb panel + WT are cache-resident; XCD-grouped grid keeps the panel's 4
// col-blocks on one XCD). 128x128 block, 4 waves 2x2, full unroll: 64 b128 loads
// + 128 MFMAs per wave, compiler-pipelined. Swapped-operand C^T frags. ----
__global__ __launch_bounds__(256) void proj_mfma_kernel(
    const unsigned short* __restrict__ featb, const unsigned short* __restrict__ WT,
    const float* __restrict__ biascat,
    unsigned short* __restrict__ el16, unsigned short* __restrict__ er16, int N)
{
    // XCD-grouped decode: b%8 = XCD; panel p = (b>>3 / 4)*8 + (b&7); col c = (b>>3)&3
    const int b    = blockIdx.x;
    const int xcd  = b & 7;
    const int s    = b >> 3;
    const int p    = (s >> 2)*8 + xcd;
    const int c    = s & 3;
    const int row0 = p * 128;
    const int col0 = c * 128;

    const int tid  = threadIdx.x;
    const int wave = tid >> 6;
    const int lane = tid & 63;
    const int wr = (wave >> 1) * 64;
    const int wc = (wave & 1) * 64;
    const int l15 = lane & 15;
    const int kg  = lane >> 4;          // 0..3

    const unsigned short* __restrict__ ar[4];
    const unsigned short* __restrict__ br[4];
    #pragma unroll
    for (int m = 0; m < 4; ++m) ar[m] = featb + (size_t)(row0 + wr + m*16 + l15)*D;
    #pragma unroll
    for (int n = 0; n < 4; ++n) br[n] = WT    + (size_t)(col0 + wc + n*16 + l15)*D;

    f32x4 acc[4][4] = {};

    #pragma unroll
    for (int t = 0; t < 4; ++t) {
        #pragma unroll
        for (int ks = 0; ks < 2; ++ks) {
            const int ko = t*64 + (kg + ks*4)*8;
            bf16x8 af[4], bf[4];
            #pragma unroll
            for (int m = 0; m < 4; ++m) af[m] = *(const bf16x8*)(ar[m] + ko);
            #pragma unroll
            for (int n = 0; n < 4; ++n) bf[n] = *(const bf16x8*)(br[n] + ko);
            #pragma unroll
            for (int m = 0; m < 4; ++m)
                #pragma unroll
                for (int n = 0; n < 4; ++n)
                    acc[m][n] = __builtin_amdgcn_mfma_f32_16x16x32_bf16(bf[n], af[m], acc[m][n], 0, 0, 0);
        }
    }

    // epilogue: C^T frag -> row = row0+wr+m*16+l15, cols = col0+wc+n*16+kg*4 .. +3
    unsigned short* __restrict__ dstp = (col0 < 256) ? el16 : er16;
    const int ccbase = col0 & 255;
    #pragma unroll
    for (int m = 0; m < 4; ++m) {
        int row = row0 + wr + m*16 + l15;
        if (row >= N) continue;
        #pragma unroll
        for (int n = 0; n < 4; ++n) {
            int cw = wc + n*16 + kg*4;
            float4 b4 = *(const float4*)(biascat + col0 + cw);
            ushort4 o;
            o.x = f2bf(acc[m][n][0] + b4.x);
            o.y = f2bf(acc[m][n][1] + b4.y);
            o.z = f2bf(acc[m][n][2] + b4.z);
            o.w = f2bf(acc[m][n][3] + b4.w);
            *(ushort4*)(dstp + (size_t)row*D + ccbase + cw) = o;
        }
    }
}

// ---------------- CSR build ----------------
__global__ void count_kernel(const int* __restrict__ dst, int* __restrict__ deg, int E){
    int e = blockIdx.x*blockDim.x + threadIdx.x;
    if (e < E) atomicAdd(&deg[dst[e]], 1);
}

__global__ __launch_bounds__(256) void scan1_kernel(const int* __restrict__ deg,
                                                    int* __restrict__ incl,
                                                    int* __restrict__ bsum, int N){
    __shared__ int s[256];
    int i = blockIdx.x*256 + threadIdx.x;
    int v = (i < N) ? deg[i] : 0;
    s[threadIdx.x] = v;
    __syncthreads();
    #pragma unroll
    for (int off = 1; off < 256; off <<= 1){
        int t = (threadIdx.x >= off) ? s[threadIdx.x - off] : 0;
        __syncthreads();
        s[threadIdx.x] += t;
        __syncthreads();
    }
    if (i < N) incl[i] = s[threadIdx.x];
    if (threadIdx.x == 255) bsum[blockIdx.x] = s[255];
}

__global__ __launch_bounds__(512) void scan2_kernel(int* __restrict__ bsum, int nb){
    __shared__ int s[512];
    int t = threadIdx.x;
    int v = (t < nb) ? bsum[t] : 0;
    s[t] = v;
    __syncthreads();
    #pragma unroll
    for (int off = 1; off < 512; off <<= 1){
        int u = (t >= off) ? s[t - off] : 0;
        __syncthreads();
        s[t] += u;
        __syncthreads();
    }
    if (t < nb) bsum[t] = s[t] - v;   // exclusive
}

__global__ __launch_bounds__(256) void scan3_kernel(const int* __restrict__ deg,
                                                    const int* __restrict__ incl,
                                                    const int* __restrict__ bsum,
                                                    int* __restrict__ rowstart,
                                                    int* __restrict__ cursor, int N){
    int i = blockIdx.x*256 + threadIdx.x;
    if (i < N){
        int st = incl[i] - deg[i] + bsum[blockIdx.x];
        rowstart[i] = st;
        cursor[i]   = st;
    }
}

// write SOURCE NODE id directly into CSR slot (no eid indirection)
__global__ void scatter_kernel(const int* __restrict__ dst, const int* __restrict__ src,
                               int* __restrict__ cursor, int* __restrict__ srcs, int E){
    int e = blockIdx.x*blockDim.x + threadIdx.x;
    if (e < E){
        int pos = atomicAdd(&cursor[dst[e]], 1);
        srcs[pos] = src[e];
    }
}

// ---------------- fused score + online-softmax + aggregate (one wave / dst) -------
// 4-edge batches: 4 gathers in flight, 4 independent shuffle-reduce chains.
__global__ __launch_bounds__(256) void gat_node_kernel(
    const unsigned short* __restrict__ el16, const unsigned short* __restrict__ er16,
    const float* __restrict__ attn, const int* __restrict__ srcs,
    const int* __restrict__ rowstart, const int* __restrict__ degv,
    float* __restrict__ out, int N)
{
    int node = blockIdx.x*4 + (threadIdx.x >> 6);
    if (node >= N) return;
    int lane = threadIdx.x & 63;
    float4 o = make_float4(0.f,0.f,0.f,0.f);
    int deg = degv[node];
    float* op = out + (size_t)node*D + lane*4;
    if (deg == 0){ *(float4*)op = o; return; }

    ushort4 rv = *(const ushort4*)(er16 + (size_t)node*D + lane*4);
    float4 r4 = make_float4(b2f(rv.x), b2f(rv.y), b2f(rv.z), b2f(rv.w));
    float4 a4 = *(const float4*)(attn + lane*4);
    int start = rowstart[node];

    float m = -INFINITY, ssum = 0.f;
    for (int base = 0; base < deg; base += 4){
        int cnt = deg - base; if (cnt > 4) cnt = 4;
        float4 l[4]; float p[4];
        #pragma unroll
        for (int j = 0; j < 4; ++j){
            int k = base + j; if (k >= deg) k = deg - 1;
            int sn = srcs[start + k];
            ushort4 lv = *(const ushort4*)(el16 + (size_t)sn*D + lane*4);
            l[j] = make_float4(b2f(lv.x), b2f(lv.y), b2f(lv.z), b2f(lv.w));
        }
        #pragma unroll
        for (int j = 0; j < 4; ++j){
            float x, pp = 0.f;
            x = l[j].x + r4.x; pp += (x > 0.f ? x : NEG*x) * a4.x;
            x = l[j].y + r4.y; pp += (x > 0.f ? x : NEG*x) * a4.y;
            x = l[j].z + r4.z; pp += (x > 0.f ? x : NEG*x) * a4.z;
            x = l[j].w + r4.w; pp += (x > 0.f ? x : NEG*x) * a4.w;
            p[j] = pp;
        }
        #pragma unroll
        for (int off = 32; off > 0; off >>= 1){
            #pragma unroll
            for (int j = 0; j < 4; ++j) p[j] += __shfl_xor(p[j], off, 64);
        }
        #pragma unroll
        for (int j = 0; j < 4; ++j){
            if (j >= cnt) break;
            float newm  = fmaxf(m, p[j]);
            float scale = __expf(m - newm);
            float w     = __expf(p[j] - newm);
            ssum = ssum*scale + w;
            o.x = o.x*scale + w*l[j].x;
            o.y = o.y*scale + w*l[j].y;
            o.z = o.z*scale + w*l[j].z;
            o.w = o.w*scale + w*l[j].w;
            m = newm;
        }
    }
    float inv = 1.f/ssum;
    o.x *= inv; o.y *= inv; o.z *= inv; o.w *= inv;
    *(float4*)op = o;
}

extern "C" void kernel_launch(void* const* d_in, const int* in_sizes, int n_in,
                              void* d_out, int out_size, void* d_ws, size_t ws_size,
                              hipStream_t stream)
{
    const float* feat = (const float*)d_in[0];
    const float* Wsrc = (const float*)d_in[1];
    const float* bsrc = (const float*)d_in[2];
    const float* Wdst = (const float*)d_in[3];
    const float* bdst = (const float*)d_in[4];
    const float* attn = (const float*)d_in[5];
    const int*   src  = (const int*)d_in[6];
    const int*   dst  = (const int*)d_in[7];
    const int N = in_sizes[0] / D;
    const int E = in_sizes[6];
    const int NPAD = ((N + 1023)/1024)*1024;   // panels (NPAD/128) divisible by 8
    const int NP = NPAD / 128;
    float* out = (float*)d_out;

    // ws: el16[N*D] er16[N*D] | deg incl rowstart cursor (N ints) | bsum[512] | srcs[E]
    //     | WT[512*256] | biascat[512 f32] | featb[NPAD*256]
    unsigned short* el16 = (unsigned short*)d_ws;
    unsigned short* er16 = el16 + (size_t)N*D;
    int* deg      = (int*)(er16 + (size_t)N*D);
    int* incl     = deg + N;
    int* rowstart = incl + N;
    int* cursor   = rowstart + N;
    int* bsum     = cursor + N;
    int* srcs     = bsum + 512;
    unsigned short* WT = (unsigned short*)(srcs + E);
    float* biascat = (float*)(WT + (size_t)512*D);
    unsigned short* featb = (unsigned short*)(biascat + 512);

    const int nb = (N + 255)/256;

    hipMemsetAsync(deg, 0, (size_t)N*sizeof(int), stream);

    prep_w_kernel<<<64, 256, 0, stream>>>(Wsrc, Wdst, bsrc, bdst, WT, biascat);
    prep_feat_kernel<<<4096, 256, 0, stream>>>(feat, featb, N, NPAD);

    proj_mfma_kernel<<<4*NP, 256, 0, stream>>>(featb, WT, biascat, el16, er16, N);

    count_kernel<<<(E + 255)/256, 256, 0, stream>>>(dst, deg, E);
    scan1_kernel<<<nb, 256, 0, stream>>>(deg, incl, bsum, N);
    scan2_kernel<<<1, 512, 0, stream>>>(bsum, nb);
    scan3_kernel<<<nb, 256, 0, stream>>>(deg, incl, bsum, rowstart, cursor, N);
    scatter_kernel<<<(E + 255)/256, 256, 0, stream>>>(dst, src, cursor, srcs, E);

    gat_node_kernel<<<(N + 3)/4, 256, 0, stream>>>(el16, er16, attn, srcs,
                                                   rowstart, deg, out, N);
}

// Round 15
// 200.118 us; speedup vs baseline: 1.2491x; 1.2491x over previous
//
#include <hip/hip_runtime.h>
#include <cstdint>
#include <cmath>

#define D 256
#define NEG 0.2f
#define BK 64
#define NT (D/BK)   // 4 K-tiles

typedef __attribute__((ext_vector_type(8))) __bf16 bf16x8;
typedef __attribute__((ext_vector_type(8))) unsigned short ushort8;
typedef __attribute__((ext_vector_type(4))) float f32x4;

__device__ __forceinline__ unsigned short f2bf(float f){
    unsigned u = __float_as_uint(f);
    return (unsigned short)((u + 0x7fffu + ((u >> 16) & 1u)) >> 16);  // RNE
}
__device__ __forceinline__ float b2f(unsigned short u){
    return __uint_as_float(((unsigned)u) << 16);
}

// async global->LDS, 16B per lane; LDS dest is WAVE-UNIFORM base (+lane*16 by HW)
__device__ __forceinline__ void gload_lds16(const void* g, void* l){
    __builtin_amdgcn_global_load_lds(
        (const __attribute__((address_space(1))) unsigned int*)g,
        (__attribute__((address_space(3))) unsigned int*)l, 16, 0, 0);
}

// ---- prep W: WT[col][k] bf16, transposed, unit-swizzled (u&24)|((u^col)&7) ----
__global__ __launch_bounds__(256) void prep_w_kernel(
    const float* __restrict__ Wsrc, const float* __restrict__ Wdst,
    const float* __restrict__ bsrc, const float* __restrict__ bdst,
    unsigned short* __restrict__ WT, float* __restrict__ biascat)
{
    int idx = blockIdx.x*256 + threadIdx.x;     // 512 cols * 32 units = 16384
    int col = idx >> 5;
    int u   = idx & 31;
    int gu  = (u & 24) | ((u ^ col) & 7);
    const float* W = (col < 256) ? Wsrc : Wdst;
    int c = col & 255;
    ushort8 o;
    #pragma unroll
    for (int j = 0; j < 8; ++j)
        o[j] = f2bf(W[(size_t)(gu*8 + j)*D + c]);
    *(ushort8*)(WT + (size_t)col*D + u*8) = o;
    if (idx < 512) biascat[idx] = (idx < 256) ? bsrc[idx] : bdst[idx-256];
}

// ---- prep feat: featb = bf16(feat), unit-swizzled, zero-padded to NPAD rows ----
__global__ __launch_bounds__(256) void prep_feat_kernel(
    const float* __restrict__ feat, unsigned short* __restrict__ featb, int N, int NPAD)
{
    int total = NPAD * 32;   // 16B units
    for (int idx = blockIdx.x*256 + threadIdx.x; idx < total; idx += gridDim.x*256){
        int r = idx >> 5;
        int u = idx & 31;
        ushort8 o;
        if (r < N){
            int gu = (u & 24) | ((u ^ r) & 7);
            const float* s = feat + (size_t)r*D + gu*8;
            float4 a = *(const float4*)s;
            float4 b = *(const float4*)(s + 4);
            o[0]=f2bf(a.x); o[1]=f2bf(a.y); o[2]=f2bf(a.z); o[3]=f2bf(a.w);
            o[4]=f2bf(b.x); o[5]=f2bf(b.y); o[6]=f2bf(b.z); o[7]=f2bf(b.w);
        } else {
            #pragma unroll
            for (int j = 0; j < 8; ++j) o[j] = 0;
        }
        *(ushort8*)(featb + (size_t)r*D + u*8) = o;
    }
}

// ---- bf16 MFMA projection: 256x256 block, 8 waves (wave tile 64x128 = 4x8 frags),
// BK=64, double-buffered gload_lds staging, counted vmcnt(8), XCD-grouped grid.
// Swapped-operand MFMA -> C^T frags -> coalesced ushort4 bf16 stores. ----
__global__ __launch_bounds__(512) void proj_mfma_kernel(
    const unsigned short* __restrict__ featb, const unsigned short* __restrict__ WT,
    const float* __restrict__ biascat,
    unsigned short* __restrict__ el16, unsigned short* __restrict__ er16, int N)
{
    __shared__ unsigned short As[2][256*BK];   // 2 x 32 KB
    __shared__ unsigned short Bs[2][256*BK];   // 2 x 32 KB

    // XCD-grouped decode: xcd = b&7; j = b>>3 enumerates that XCD's work:
    // panel p = (j>>1)*8 + xcd, col-half c = j&1.
    const int b    = blockIdx.x;
    const int xcd  = b & 7;
    const int j    = b >> 3;
    const int p    = (j >> 1)*8 + xcd;
    const int c    = j & 1;
    const int row0 = p * 256;
    const int col0 = c * 256;

    const int tid  = threadIdx.x;
    const int wave = tid >> 6;          // 0..7
    const int lane = tid & 63;
    const int wr = (wave >> 1) * 64;    // 0,64,128,192
    const int wc = (wave & 1) * 128;    // 0,128
    const int l15 = lane & 15;
    const int kg  = lane >> 4;          // 0..3

    const int sr = (wave << 3) + (lane >> 3);   // staging row 0..63 per round
    const int sc = (lane & 7) * 8;              // elem offset of 16B unit

    f32x4 acc[4][8] = {};

    // prologue: stage tile 0 into buffer 0 (8 gloads/wave)
    #pragma unroll
    for (int r4 = 0; r4 < 4; ++r4) {
        int ar = r4*64 + sr;
        gload_lds16(featb + (size_t)(row0 + ar)*D + 0 + sc, &As[0][(r4*64 + wave*8)*BK]);
        gload_lds16(WT    + (size_t)(col0 + ar)*D + 0 + sc, &Bs[0][(r4*64 + wave*8)*BK]);
    }

    for (int t = 0; t < NT; ++t) {
        const int cur = t & 1;
        if (t + 1 < NT) {
            int k0 = (t + 1) * BK;
            #pragma unroll
            for (int r4 = 0; r4 < 4; ++r4) {
                int ar = r4*64 + sr;
                gload_lds16(featb + (size_t)(row0 + ar)*D + k0 + sc,
                            &As[cur ^ 1][(r4*64 + wave*8)*BK]);
                gload_lds16(WT    + (size_t)(col0 + ar)*D + k0 + sc,
                            &Bs[cur ^ 1][(r4*64 + wave*8)*BK]);
            }
            asm volatile("s_waitcnt vmcnt(8)" ::: "memory");  // tile t done, t+1 in flight
        } else {
            asm volatile("s_waitcnt vmcnt(0)" ::: "memory");
        }
        __builtin_amdgcn_s_barrier();
        __builtin_amdgcn_sched_barrier(0);

        #pragma unroll
        for (int ks = 0; ks < 2; ++ks) {
            bf16x8 af[4], bfr[8];
            #pragma unroll
            for (int m = 0; m < 4; ++m){
                int row = wr + m*16 + l15;
                int cc = ((kg + ks*4) ^ (row & 7)) * 8;   // un-swizzle on read
                af[m] = *(const bf16x8*)&As[cur][row*BK + cc];
            }
            #pragma unroll
            for (int n = 0; n < 8; ++n){
                int row = wc + n*16 + l15;
                int cc = ((kg + ks*4) ^ (row & 7)) * 8;
                bfr[n] = *(const bf16x8*)&Bs[cur][row*BK + cc];
            }
            #pragma unroll
            for (int m = 0; m < 4; ++m)
                #pragma unroll
                for (int n = 0; n < 8; ++n)
                    acc[m][n] = __builtin_amdgcn_mfma_f32_16x16x32_bf16(bfr[n], af[m], acc[m][n], 0, 0, 0);
        }
        __builtin_amdgcn_sched_barrier(0);
        __builtin_amdgcn_s_barrier();   // all reads of buf[cur] done before restage
    }

    // epilogue: C^T frag -> row = row0+wr+m*16+l15, cols = col0 + wc+n*16+kg*4 .. +3
    unsigned short* __restrict__ dstp = (col0 < 256) ? el16 : er16;
    #pragma unroll
    for (int m = 0; m < 4; ++m) {
        int row = row0 + wr + m*16 + l15;
        if (row >= N) continue;
        #pragma unroll
        for (int n = 0; n < 8; ++n) {
            int cw = wc + n*16 + kg*4;        // 0..255 within half
            float4 b4 = *(const float4*)(biascat + col0 + cw);
            ushort4 o;
            o.x = f2bf(acc[m][n][0] + b4.x);
            o.y = f2bf(acc[m][n][1] + b4.y);
            o.z = f2bf(acc[m][n][2] + b4.z);
            o.w = f2bf(acc[m][n][3] + b4.w);
            *(ushort4*)(dstp + (size_t)row*D + cw) = o;
        }
    }
}

// ---------------- CSR build ----------------
__global__ void count_kernel(const int* __restrict__ dst, int* __restrict__ deg, int E){
    int e = blockIdx.x*blockDim.x + threadIdx.x;
    if (e < E) atomicAdd(&deg[dst[e]], 1);
}

__global__ __launch_bounds__(256) void scan1_kernel(const int* __restrict__ deg,
                                                    int* __restrict__ incl,
                                                    int* __restrict__ bsum, int N){
    __shared__ int s[256];
    int i = blockIdx.x*256 + threadIdx.x;
    int v = (i < N) ? deg[i] : 0;
    s[threadIdx.x] = v;
    __syncthreads();
    #pragma unroll
    for (int off = 1; off < 256; off <<= 1){
        int t = (threadIdx.x >= off) ? s[threadIdx.x - off] : 0;
        __syncthreads();
        s[threadIdx.x] += t;
        __syncthreads();
    }
    if (i < N) incl[i] = s[threadIdx.x];
    if (threadIdx.x == 255) bsum[blockIdx.x] = s[255];
}

__global__ __launch_bounds__(512) void scan2_kernel(int* __restrict__ bsum, int nb){
    __shared__ int s[512];
    int t = threadIdx.x;
    int v = (t < nb) ? bsum[t] : 0;
    s[t] = v;
    __syncthreads();
    #pragma unroll
    for (int off = 1; off < 512; off <<= 1){
        int u = (t >= off) ? s[t - off] : 0;
        __syncthreads();
        s[t] += u;
        __syncthreads();
    }
    if (t < nb) bsum[t] = s[t] - v;   // exclusive
}

__global__ __launch_bounds__(256) void scan3_kernel(const int* __restrict__ deg,
                                                    const int* __restrict__ incl,
                                                    const int* __restrict__ bsum,
                                                    int* __restrict__ rowstart,
                                                    int* __restrict__ cursor, int N){
    int i = blockIdx.x*256 + threadIdx.x;
    if (i < N){
        int st = incl[i] - deg[i] + bsum[blockIdx.x];
        rowstart[i] = st;
        cursor[i]   = st;
    }
}

// write SOURCE NODE id directly into CSR slot (no eid indirection)
__global__ void scatter_kernel(const int* __restrict__ dst, const int* __restrict__ src,
                               int* __restrict__ cursor, int* __restrict__ srcs, int E){
    int e = blockIdx.x*blockDim.x + threadIdx.x;
    if (e < E){
        int pos = atomicAdd(&cursor[dst[e]], 1);
        srcs[pos] = src[e];
    }
}

// ---------------- fused score + online-softmax + aggregate (one wave / dst) -------
// 4-edge batches: 4 gathers in flight, 4 independent shuffle-reduce chains.
__global__ __launch_bounds__(256) void gat_node_kernel(
    const unsigned short* __restrict__ el16, const unsigned short* __restrict__ er16,
    const float* __restrict__ attn, const int* __restrict__ srcs,
    const int* __restrict__ rowstart, const int* __restrict__ degv,
    float* __restrict__ out, int N)
{
    int node = blockIdx.x*4 + (threadIdx.x >> 6);
    if (node >= N) return;
    int lane = threadIdx.x & 63;
    float4 o = make_float4(0.f,0.f,0.f,0.f);
    int deg = degv[node];
    float* op = out + (size_t)node*D + lane*4;
    if (deg == 0){ *(float4*)op = o; return; }

    ushort4 rv = *(const ushort4*)(er16 + (size_t)node*D + lane*4);
    float4 r4 = make_float4(b2f(rv.x), b2f(rv.y), b2f(rv.z), b2f(rv.w));
    float4 a4 = *(const float4*)(attn + lane*4);
    int start = rowstart[node];

    float m = -INFINITY, ssum = 0.f;
    for (int base = 0; base < deg; base += 4){
        int cnt = deg - base; if (cnt > 4) cnt = 4;
        float4 l[4]; float p[4];
        #pragma unroll
        for (int j = 0; j < 4; ++j){
            int k = base + j; if (k >= deg) k = deg - 1;
            int sn = srcs[start + k];
            ushort4 lv = *(const ushort4*)(el16 + (size_t)sn*D + lane*4);
            l[j] = make_float4(b2f(lv.x), b2f(lv.y), b2f(lv.z), b2f(lv.w));
        }
        #pragma unroll
        for (int j = 0; j < 4; ++j){
            float x, pp = 0.f;
            x = l[j].x + r4.x; pp += (x > 0.f ? x : NEG*x) * a4.x;
            x = l[j].y + r4.y; pp += (x > 0.f ? x : NEG*x) * a4.y;
            x = l[j].z + r4.z; pp += (x > 0.f ? x : NEG*x) * a4.z;
            x = l[j].w + r4.w; pp += (x > 0.f ? x : NEG*x) * a4.w;
            p[j] = pp;
        }
        #pragma unroll
        for (int off = 32; off > 0; off >>= 1){
            #pragma unroll
            for (int j = 0; j < 4; ++j) p[j] += __shfl_xor(p[j], off, 64);
        }
        #pragma unroll
        for (int j = 0; j < 4; ++j){
            if (j >= cnt) break;
            float newm  = fmaxf(m, p[j]);
            float scale = __expf(m - newm);
            float w     = __expf(p[j] - newm);
            ssum = ssum*scale + w;
            o.x = o.x*scale + w*l[j].x;
            o.y = o.y*scale + w*l[j].y;
            o.z = o.z*scale + w*l[j].z;
            o.w = o.w*scale + w*l[j].w;
            m = newm;
        }
    }
    float inv = 1.f/ssum;
    o.x *= inv; o.y *= inv; o.z *= inv; o.w *= inv;
    *(float4*)op = o;
}

extern "C" void kernel_launch(void* const* d_in, const int* in_sizes, int n_in,
                              void* d_out, int out_size, void* d_ws, size_t ws_size,
                              hipStream_t stream)
{
    const float* feat = (const float*)d_in[0];
    const float* Wsrc = (const float*)d_in[1];
    const float* bsrc = (const float*)d_in[2];
    const float* Wdst = (const float*)d_in[3];
    const float* bdst = (const float*)d_in[4];
    const float* attn = (const float*)d_in[5];
    const int*   src  = (const int*)d_in[6];
    const int*   dst  = (const int*)d_in[7];
    const int N = in_sizes[0] / D;
    const int E = in_sizes[6];
    // 256-row panels, panel count divisible by 8 (XCD decode needs (2*NP)%8==0)
    const int NP   = ((N + 255)/256 + 7) & ~7;
    const int NPAD = NP * 256;
    float* out = (float*)d_out;

    // ws: el16[N*D] er16[N*D] | deg incl rowstart cursor (N ints) | bsum[512] | srcs[E]
    //     | WT[512*256] | biascat[512 f32] | featb[NPAD*256]
    unsigned short* el16 = (unsigned short*)d_ws;
    unsigned short* er16 = el16 + (size_t)N*D;
    int* deg      = (int*)(er16 + (size_t)N*D);
    int* incl     = deg + N;
    int* rowstart = incl + N;
    int* cursor   = rowstart + N;
    int* bsum     = cursor + N;
    int* srcs     = bsum + 512;
    unsigned short* WT = (unsigned short*)(srcs + E);
    float* biascat = (float*)(WT + (size_t)512*D);
    unsigned short* featb = (unsigned short*)(biascat + 512);

    const int nb = (N + 255)/256;

    hipMemsetAsync(deg, 0, (size_t)N*sizeof(int), stream);

    prep_w_kernel<<<64, 256, 0, stream>>>(Wsrc, Wdst, bsrc, bdst, WT, biascat);
    prep_feat_kernel<<<4096, 256, 0, stream>>>(feat, featb, N, NPAD);

    proj_mfma_kernel<<<2*NP, 512, 0, stream>>>(featb, WT, biascat, el16, er16, N);

    count_kernel<<<(E + 255)/256, 256, 0, stream>>>(dst, deg, E);
    scan1_kernel<<<nb, 256, 0, stream>>>(deg, incl, bsum, N);
    scan2_kernel<<<1, 512, 0, stream>>>(bsum, nb);
    scan3_kernel<<<nb, 256, 0, stream>>>(deg, incl, bsum, rowstart, cursor, N);
    scatter_kernel<<<(E + 255)/256, 256, 0, stream>>>(dst, src, cursor, srcs, E);

    gat_node_kernel<<<(N + 3)/4, 256, 0, stream>>>(el16, er16, attn, srcs,
                                                   rowstart, deg, out, N);
}

// Round 16
// 191.607 us; speedup vs baseline: 1.3046x; 1.0444x over previous
//
#include <hip/hip_runtime.h>
#include <cstdint>
#include <cmath>

#define D 256
#define NEG 0.2f
#define BK 64
#define NT (D/BK)   // 4 K-tiles

typedef __attribute__((ext_vector_type(8))) __bf16 bf16x8;
typedef __attribute__((ext_vector_type(8))) unsigned short ushort8;
typedef __attribute__((ext_vector_type(4))) float f32x4;

__device__ __forceinline__ unsigned short f2bf(float f){
    unsigned u = __float_as_uint(f);
    return (unsigned short)((u + 0x7fffu + ((u >> 16) & 1u)) >> 16);  // RNE
}
__device__ __forceinline__ float b2f(unsigned short u){
    return __uint_as_float(((unsigned)u) << 16);
}

// async global->LDS, 16B per lane; LDS dest is WAVE-UNIFORM base (+lane*16 by HW)
__device__ __forceinline__ void gload_lds16(const void* g, void* l){
    __builtin_amdgcn_global_load_lds(
        (const __attribute__((address_space(1))) unsigned int*)g,
        (__attribute__((address_space(3))) unsigned int*)l, 16, 0, 0);
}

// ---- prep W: WT[col][k] bf16, transposed, unit-swizzled (u&24)|((u^col)&7) ----
__global__ __launch_bounds__(256) void prep_w_kernel(
    const float* __restrict__ Wsrc, const float* __restrict__ Wdst,
    const float* __restrict__ bsrc, const float* __restrict__ bdst,
    unsigned short* __restrict__ WT, float* __restrict__ biascat)
{
    int idx = blockIdx.x*256 + threadIdx.x;     // 512 cols * 32 units = 16384
    int col = idx >> 5;
    int u   = idx & 31;
    int gu  = (u & 24) | ((u ^ col) & 7);
    const float* W = (col < 256) ? Wsrc : Wdst;
    int c = col & 255;
    ushort8 o;
    #pragma unroll
    for (int j = 0; j < 8; ++j)
        o[j] = f2bf(W[(size_t)(gu*8 + j)*D + c]);
    *(ushort8*)(WT + (size_t)col*D + u*8) = o;
    if (idx < 512) biascat[idx] = (idx < 256) ? bsrc[idx] : bdst[idx-256];
}

// ---- prep feat: featb = bf16(feat), unit-swizzled, zero-padded to NPAD rows ----
__global__ __launch_bounds__(256) void prep_feat_kernel(
    const float* __restrict__ feat, unsigned short* __restrict__ featb, int N, int NPAD)
{
    int total = NPAD * 32;   // 16B units
    for (int idx = blockIdx.x*256 + threadIdx.x; idx < total; idx += gridDim.x*256){
        int r = idx >> 5;
        int u = idx & 31;
        ushort8 o;
        if (r < N){
            int gu = (u & 24) | ((u ^ r) & 7);
            const float* s = feat + (size_t)r*D + gu*8;
            float4 a = *(const float4*)s;
            float4 b = *(const float4*)(s + 4);
            o[0]=f2bf(a.x); o[1]=f2bf(a.y); o[2]=f2bf(a.z); o[3]=f2bf(a.w);
            o[4]=f2bf(b.x); o[5]=f2bf(b.y); o[6]=f2bf(b.z); o[7]=f2bf(b.w);
        } else {
            #pragma unroll
            for (int j = 0; j < 8; ++j) o[j] = 0;
        }
        *(ushort8*)(featb + (size_t)r*D + u*8) = o;
    }
}

// ---- bf16 MFMA projection (r13 structure, measured 63 us): 128x128 tile, BK=64,
// double-buffered gload_lds staging, counted vmcnt(8), XCD-grouped 1D grid ----
__global__ __launch_bounds__(256) void proj_mfma_kernel(
    const unsigned short* __restrict__ featb, const unsigned short* __restrict__ WT,
    const float* __restrict__ biascat,
    unsigned short* __restrict__ el16, unsigned short* __restrict__ er16, int N)
{
    __shared__ unsigned short As[2][128*BK];   // 2 x 16 KB
    __shared__ unsigned short Bs[2][128*BK];   // 2 x 16 KB

    // XCD-grouped decode: b%8 = XCD; panel p = (b>>3 / 4)*8 + (b&7); col c = (b>>3)&3
    const int b    = blockIdx.x;
    const int xcd  = b & 7;
    const int s    = b >> 3;
    const int p    = (s >> 2)*8 + xcd;
    const int c    = s & 3;
    const int row0 = p * 128;
    const int col0 = c * 128;

    const int tid  = threadIdx.x;
    const int wave = tid >> 6;
    const int lane = tid & 63;
    const int wr = (wave >> 1) * 64;
    const int wc = (wave & 1) * 64;
    const int l15 = lane & 15;
    const int kg  = lane >> 4;          // 0..3

    const int sr = (wave << 3) + (lane >> 3);   // row within 32-row chunk
    const int sc = (lane & 7) * 8;              // elem offset of 16B unit

    f32x4 acc[4][4] = {};

    // prologue: stage tile 0 into buffer 0 (8 loads/wave)
    #pragma unroll
    for (int r4 = 0; r4 < 4; ++r4) {
        int ar = r4*32 + sr;
        gload_lds16(featb + (size_t)(row0 + ar)*D + 0 + sc, &As[0][(r4*32 + wave*8)*BK]);
        gload_lds16(WT    + (size_t)(col0 + ar)*D + 0 + sc, &Bs[0][(r4*32 + wave*8)*BK]);
    }

    for (int t = 0; t < NT; ++t) {
        const int cur = t & 1;
        if (t + 1 < NT) {
            int k0 = (t + 1) * BK;
            #pragma unroll
            for (int r4 = 0; r4 < 4; ++r4) {
                int ar = r4*32 + sr;
                gload_lds16(featb + (size_t)(row0 + ar)*D + k0 + sc,
                            &As[cur ^ 1][(r4*32 + wave*8)*BK]);
                gload_lds16(WT    + (size_t)(col0 + ar)*D + k0 + sc,
                            &Bs[cur ^ 1][(r4*32 + wave*8)*BK]);
            }
            asm volatile("s_waitcnt vmcnt(8)" ::: "memory");  // tile t done, t+1 in flight
        } else {
            asm volatile("s_waitcnt vmcnt(0)" ::: "memory");
        }
        __builtin_amdgcn_s_barrier();
        __builtin_amdgcn_sched_barrier(0);

        #pragma unroll
        for (int ks = 0; ks < 2; ++ks) {
            bf16x8 af[4], bfr[4];
            #pragma unroll
            for (int m = 0; m < 4; ++m){
                int row = wr + m*16 + l15;
                int cc = ((kg + ks*4) ^ (row & 7)) * 8;   // un-swizzle on read
                af[m] = *(const bf16x8*)&As[cur][row*BK + cc];
            }
            #pragma unroll
            for (int n = 0; n < 4; ++n){
                int row = wc + n*16 + l15;
                int cc = ((kg + ks*4) ^ (row & 7)) * 8;
                bfr[n] = *(const bf16x8*)&Bs[cur][row*BK + cc];
            }
            #pragma unroll
            for (int m = 0; m < 4; ++m)
                #pragma unroll
                for (int n = 0; n < 4; ++n)
                    acc[m][n] = __builtin_amdgcn_mfma_f32_16x16x32_bf16(bfr[n], af[m], acc[m][n], 0, 0, 0);
        }
        __builtin_amdgcn_sched_barrier(0);
        __builtin_amdgcn_s_barrier();   // all reads of buf[cur] done before restage
    }

    // epilogue: C^T frag -> row = row0+wr+m*16+l15, cols = col0+wc+n*16+kg*4 .. +3
    unsigned short* __restrict__ dstp = (col0 < 256) ? el16 : er16;
    const int ccbase = col0 & 255;
    #pragma unroll
    for (int m = 0; m < 4; ++m) {
        int row = row0 + wr + m*16 + l15;
        if (row >= N) continue;
        #pragma unroll
        for (int n = 0; n < 4; ++n) {
            int cw = wc + n*16 + kg*4;
            float4 b4 = *(const float4*)(biascat + col0 + cw);
            ushort4 o;
            o.x = f2bf(acc[m][n][0] + b4.x);
            o.y = f2bf(acc[m][n][1] + b4.y);
            o.z = f2bf(acc[m][n][2] + b4.z);
            o.w = f2bf(acc[m][n][3] + b4.w);
            *(ushort4*)(dstp + (size_t)row*D + ccbase + cw) = o;
        }
    }
}

// ---------------- CSR build ----------------
__global__ void count_kernel(const int* __restrict__ dst, int* __restrict__ deg, int E){
    int e = blockIdx.x*blockDim.x + threadIdx.x;
    if (e < E) atomicAdd(&deg[dst[e]], 1);
}

__global__ __launch_bounds__(256) void scan1_kernel(const int* __restrict__ deg,
                                                    int* __restrict__ incl,
                                                    int* __restrict__ bsum, int N){
    __shared__ int s[256];
    int i = blockIdx.x*256 + threadIdx.x;
    int v = (i < N) ? deg[i] : 0;
    s[threadIdx.x] = v;
    __syncthreads();
    #pragma unroll
    for (int off = 1; off < 256; off <<= 1){
        int t = (threadIdx.x >= off) ? s[threadIdx.x - off] : 0;
        __syncthreads();
        s[threadIdx.x] += t;
        __syncthreads();
    }
    if (i < N) incl[i] = s[threadIdx.x];
    if (threadIdx.x == 255) bsum[blockIdx.x] = s[255];
}

__global__ __launch_bounds__(512) void scan2_kernel(int* __restrict__ bsum, int nb){
    __shared__ int s[512];
    int t = threadIdx.x;
    int v = (t < nb) ? bsum[t] : 0;
    s[t] = v;
    __syncthreads();
    #pragma unroll
    for (int off = 1; off < 512; off <<= 1){
        int u = (t >= off) ? s[t - off] : 0;
        __syncthreads();
        s[t] += u;
        __syncthreads();
    }
    if (t < nb) bsum[t] = s[t] - v;   // exclusive
}

__global__ __launch_bounds__(256) void scan3_kernel(const int* __restrict__ deg,
                                                    const int* __restrict__ incl,
                                                    const int* __restrict__ bsum,
                                                    int* __restrict__ rowstart,
                                                    int* __restrict__ cursor, int N){
    int i = blockIdx.x*256 + threadIdx.x;
    if (i < N){
        int st = incl[i] - deg[i] + bsum[blockIdx.x];
        rowstart[i] = st;
        cursor[i]   = st;
    }
}

// write SOURCE NODE id directly into CSR slot (no eid indirection)
__global__ void scatter_kernel(const int* __restrict__ dst, const int* __restrict__ src,
                               int* __restrict__ cursor, int* __restrict__ srcs, int E){
    int e = blockIdx.x*blockDim.x + threadIdx.x;
    if (e < E){
        int pos = atomicAdd(&cursor[dst[e]], 1);
        srcs[pos] = src[e];
    }
}

// ---------------- fused score + online-softmax + aggregate ----------------
// TWO nodes per wave: lanes 0-31 -> node A, 32-63 -> node B. Each lane covers
// 8 row elems (ushort8 16B loads). 4-edge batches => 8 gathers in flight/wave.
// 5-step shfl_xor reduce (masks 16..1 stay within each 32-lane half).
__global__ __launch_bounds__(256) void gat_node_kernel(
    const unsigned short* __restrict__ el16, const unsigned short* __restrict__ er16,
    const float* __restrict__ attn, const int* __restrict__ srcs,
    const int* __restrict__ rowstart, const int* __restrict__ degv,
    float* __restrict__ out, int N, int E)
{
    int wave = threadIdx.x >> 6;
    int lane = threadIdx.x & 63;
    int half = lane >> 5;
    int hl   = lane & 31;
    int node = blockIdx.x*8 + wave*2 + half;
    if (node >= N) return;

    int deg   = degv[node];
    int start = rowstart[node];

    ushort8 rv = *(const ushort8*)(er16 + (size_t)node*D + hl*8);
    float r[8], a[8];
    #pragma unroll
    for (int i = 0; i < 8; ++i) r[i] = b2f(rv[i]);
    float4 a0 = *(const float4*)(attn + hl*8);
    float4 a1 = *(const float4*)(attn + hl*8 + 4);
    a[0]=a0.x; a[1]=a0.y; a[2]=a0.z; a[3]=a0.w;
    a[4]=a1.x; a[5]=a1.y; a[6]=a1.z; a[7]=a1.w;

    float o[8] = {};
    float m = -INFINITY, ssum = 0.f;
    int degmax = max(deg, __shfl_xor(deg, 32, 64));   // shared loop bound

    for (int base = 0; base < degmax; base += 4){
        int cnt = deg - base;              // may be <= 0 for this half
        int sn[4];
        #pragma unroll
        for (int j = 0; j < 4; ++j){
            int idx = start + base + j;
            idx = idx < E ? idx : E - 1;   // clamp (also covers deg==0 padding)
            sn[j] = srcs[idx];
        }
        float l[4][8]; float p[4];
        #pragma unroll
        for (int j = 0; j < 4; ++j){
            ushort8 lv = *(const ushort8*)(el16 + (size_t)sn[j]*D + hl*8);
            #pragma unroll
            for (int i = 0; i < 8; ++i) l[j][i] = b2f(lv[i]);
        }
        #pragma unroll
        for (int j = 0; j < 4; ++j){
            float pp = 0.f;
            #pragma unroll
            for (int i = 0; i < 8; ++i){
                float x = l[j][i] + r[i];
                pp += (x > 0.f ? x : NEG*x) * a[i];
            }
            p[j] = pp;
        }
        #pragma unroll
        for (int off = 16; off > 0; off >>= 1){
            #pragma unroll
            for (int j = 0; j < 4; ++j) p[j] += __shfl_xor(p[j], off, 64);
        }
        #pragma unroll
        for (int j = 0; j < 4; ++j){
            if (j < cnt){
                float newm  = fmaxf(m, p[j]);
                float scale = __expf(m - newm);
                float w     = __expf(p[j] - newm);
                ssum = ssum*scale + w;
                #pragma unroll
                for (int i = 0; i < 8; ++i) o[i] = o[i]*scale + w*l[j][i];
                m = newm;
            }
        }
    }
    float inv = (deg > 0) ? 1.f/ssum : 0.f;
    float* op = out + (size_t)node*D + hl*8;
    *(float4*)op       = make_float4(o[0]*inv, o[1]*inv, o[2]*inv, o[3]*inv);
    *(float4*)(op + 4) = make_float4(o[4]*inv, o[5]*inv, o[6]*inv, o[7]*inv);
}

extern "C" void kernel_launch(void* const* d_in, const int* in_sizes, int n_in,
                              void* d_out, int out_size, void* d_ws, size_t ws_size,
                              hipStream_t stream)
{
    const float* feat = (const float*)d_in[0];
    const float* Wsrc = (const float*)d_in[1];
    const float* bsrc = (const float*)d_in[2];
    const float* Wdst = (const float*)d_in[3];
    const float* bdst = (const float*)d_in[4];
    const float* attn = (const float*)d_in[5];
    const int*   src  = (const int*)d_in[6];
    const int*   dst  = (const int*)d_in[7];
    const int N = in_sizes[0] / D;
    const int E = in_sizes[6];
    const int NPAD = ((N + 1023)/1024)*1024;   // panels (NPAD/128) divisible by 8
    const int NP = NPAD / 128;
    float* out = (float*)d_out;

    // ws: el16[N*D] er16[N*D] | deg incl rowstart cursor (N ints) | bsum[512] | srcs[E]
    //     | WT[512*256] | biascat[512 f32] | featb[NPAD*256]
    unsigned short* el16 = (unsigned short*)d_ws;
    unsigned short* er16 = el16 + (size_t)N*D;
    int* deg      = (int*)(er16 + (size_t)N*D);
    int* incl     = deg + N;
    int* rowstart = incl + N;
    int* cursor   = rowstart + N;
    int* bsum     = cursor + N;
    int* srcs     = bsum + 512;
    unsigned short* WT = (unsigned short*)(srcs + E);
    float* biascat = (float*)(WT + (size_t)512*D);
    unsigned short* featb = (unsigned short*)(biascat + 512);

    const int nb = (N + 255)/256;

    hipMemsetAsync(deg, 0, (size_t)N*sizeof(int), stream);

    prep_w_kernel<<<64, 256, 0, stream>>>(Wsrc, Wdst, bsrc, bdst, WT, biascat);
    prep_feat_kernel<<<4096, 256, 0, stream>>>(feat, featb, N, NPAD);

    proj_mfma_kernel<<<4*NP, 256, 0, stream>>>(featb, WT, biascat, el16, er16, N);

    count_kernel<<<(E + 255)/256, 256, 0, stream>>>(dst, deg, E);
    scan1_kernel<<<nb, 256, 0, stream>>>(deg, incl, bsum, N);
    scan2_kernel<<<1, 512, 0, stream>>>(bsum, nb);
    scan3_kernel<<<nb, 256, 0, stream>>>(deg, incl, bsum, rowstart, cursor, N);
    scatter_kernel<<<(E + 255)/256, 256, 0, stream>>>(dst, src, cursor, srcs, E);

    gat_node_kernel<<<(N + 7)/8, 256, 0, stream>>>(el16, er16, attn, srcs,
                                                   rowstart, deg, out, N, E);
}

// Round 17
// 178.552 us; speedup vs baseline: 1.3999x; 1.0731x over previous
//
#include <hip/hip_runtime.h>
#include <cstdint>
#include <cmath>

#define D 256
#define NEG 0.2f
#define BK 64
#define NT (D/BK)   // 4 K-tiles

typedef __attribute__((ext_vector_type(8))) __bf16 bf16x8;
typedef __attribute__((ext_vector_type(8))) unsigned short ushort8;
typedef __attribute__((ext_vector_type(4))) float f32x4;

__device__ __forceinline__ unsigned short f2bf(float f){
    unsigned u = __float_as_uint(f);
    return (unsigned short)((u + 0x7fffu + ((u >> 16) & 1u)) >> 16);  // RNE
}
__device__ __forceinline__ float b2f(unsigned short u){
    return __uint_as_float(((unsigned)u) << 16);
}

// async global->LDS, 16B per lane; LDS dest is WAVE-UNIFORM base (+lane*16 by HW)
__device__ __forceinline__ void gload_lds16(const void* g, void* l){
    __builtin_amdgcn_global_load_lds(
        (const __attribute__((address_space(1))) unsigned int*)g,
        (__attribute__((address_space(3))) unsigned int*)l, 16, 0, 0);
}

// ---- fused prep: [0,64) prep_w | [64,64+CB) edge count | rest: prep_feat ----
// All three phases are mutually independent; count's scattered atomics hide
// under prep_feat's HBM-bound stream.
__global__ __launch_bounds__(256) void prep_all_kernel(
    const float* __restrict__ Wsrc, const float* __restrict__ Wdst,
    const float* __restrict__ bsrc, const float* __restrict__ bdst,
    unsigned short* __restrict__ WT, float* __restrict__ biascat,
    const float* __restrict__ feat, unsigned short* __restrict__ featb,
    int N, int NPAD,
    const int* __restrict__ dst, int* __restrict__ deg, int E, int CB)
{
    const int b = blockIdx.x;
    if (b < 64) {
        // prep W: WT[col][k] bf16, transposed, unit-swizzled (u&24)|((u^col)&7)
        int idx = b*256 + threadIdx.x;          // 512 cols * 32 units = 16384
        int col = idx >> 5;
        int u   = idx & 31;
        int gu  = (u & 24) | ((u ^ col) & 7);
        const float* W = (col < 256) ? Wsrc : Wdst;
        int c = col & 255;
        ushort8 o;
        #pragma unroll
        for (int j = 0; j < 8; ++j)
            o[j] = f2bf(W[(size_t)(gu*8 + j)*D + c]);
        *(ushort8*)(WT + (size_t)col*D + u*8) = o;
        if (idx < 512) biascat[idx] = (idx < 256) ? bsrc[idx] : bdst[idx-256];
    } else if (b < 64 + CB) {
        int e = (b - 64)*256 + threadIdx.x;
        if (e < E) atomicAdd(&deg[dst[e]], 1);
    } else {
        // prep feat: featb = bf16(feat), unit-swizzled, zero-padded to NPAD rows
        int nfb   = gridDim.x - 64 - CB;
        int total = NPAD * 32;   // 16B units
        for (int idx = (b - 64 - CB)*256 + threadIdx.x; idx < total; idx += nfb*256){
            int r = idx >> 5;
            int u = idx & 31;
            ushort8 o;
            if (r < N){
                int gu = (u & 24) | ((u ^ r) & 7);
                const float* s = feat + (size_t)r*D + gu*8;
                float4 a = *(const float4*)s;
                float4 bb = *(const float4*)(s + 4);
                o[0]=f2bf(a.x); o[1]=f2bf(a.y); o[2]=f2bf(a.z); o[3]=f2bf(a.w);
                o[4]=f2bf(bb.x); o[5]=f2bf(bb.y); o[6]=f2bf(bb.z); o[7]=f2bf(bb.w);
            } else {
                #pragma unroll
                for (int j = 0; j < 8; ++j) o[j] = 0;
            }
            *(ushort8*)(featb + (size_t)r*D + u*8) = o;
        }
    }
}

// ---- bf16 MFMA projection (r13 structure, measured 63 us): 128x128 tile, BK=64,
// double-buffered gload_lds staging, counted vmcnt(8), XCD-grouped 1D grid ----
__global__ __launch_bounds__(256) void proj_mfma_kernel(
    const unsigned short* __restrict__ featb, const unsigned short* __restrict__ WT,
    const float* __restrict__ biascat,
    unsigned short* __restrict__ el16, unsigned short* __restrict__ er16, int N)
{
    __shared__ unsigned short As[2][128*BK];   // 2 x 16 KB
    __shared__ unsigned short Bs[2][128*BK];   // 2 x 16 KB

    // XCD-grouped decode: b%8 = XCD; panel p = (b>>3 / 4)*8 + (b&7); col c = (b>>3)&3
    const int b    = blockIdx.x;
    const int xcd  = b & 7;
    const int s    = b >> 3;
    const int p    = (s >> 2)*8 + xcd;
    const int c    = s & 3;
    const int row0 = p * 128;
    const int col0 = c * 128;

    const int tid  = threadIdx.x;
    const int wave = tid >> 6;
    const int lane = tid & 63;
    const int wr = (wave >> 1) * 64;
    const int wc = (wave & 1) * 64;
    const int l15 = lane & 15;
    const int kg  = lane >> 4;          // 0..3

    const int sr = (wave << 3) + (lane >> 3);   // row within 32-row chunk
    const int sc = (lane & 7) * 8;              // elem offset of 16B unit

    f32x4 acc[4][4] = {};

    // prologue: stage tile 0 into buffer 0 (8 loads/wave)
    #pragma unroll
    for (int r4 = 0; r4 < 4; ++r4) {
        int ar = r4*32 + sr;
        gload_lds16(featb + (size_t)(row0 + ar)*D + 0 + sc, &As[0][(r4*32 + wave*8)*BK]);
        gload_lds16(WT    + (size_t)(col0 + ar)*D + 0 + sc, &Bs[0][(r4*32 + wave*8)*BK]);
    }

    for (int t = 0; t < NT; ++t) {
        const int cur = t & 1;
        if (t + 1 < NT) {
            int k0 = (t + 1) * BK;
            #pragma unroll
            for (int r4 = 0; r4 < 4; ++r4) {
                int ar = r4*32 + sr;
                gload_lds16(featb + (size_t)(row0 + ar)*D + k0 + sc,
                            &As[cur ^ 1][(r4*32 + wave*8)*BK]);
                gload_lds16(WT    + (size_t)(col0 + ar)*D + k0 + sc,
                            &Bs[cur ^ 1][(r4*32 + wave*8)*BK]);
            }
            asm volatile("s_waitcnt vmcnt(8)" ::: "memory");  // tile t done, t+1 in flight
        } else {
            asm volatile("s_waitcnt vmcnt(0)" ::: "memory");
        }
        __builtin_amdgcn_s_barrier();
        __builtin_amdgcn_sched_barrier(0);

        #pragma unroll
        for (int ks = 0; ks < 2; ++ks) {
            bf16x8 af[4], bfr[4];
            #pragma unroll
            for (int m = 0; m < 4; ++m){
                int row = wr + m*16 + l15;
                int cc = ((kg + ks*4) ^ (row & 7)) * 8;   // un-swizzle on read
                af[m] = *(const bf16x8*)&As[cur][row*BK + cc];
            }
            #pragma unroll
            for (int n = 0; n < 4; ++n){
                int row = wc + n*16 + l15;
                int cc = ((kg + ks*4) ^ (row & 7)) * 8;
                bfr[n] = *(const bf16x8*)&Bs[cur][row*BK + cc];
            }
            #pragma unroll
            for (int m = 0; m < 4; ++m)
                #pragma unroll
                for (int n = 0; n < 4; ++n)
                    acc[m][n] = __builtin_amdgcn_mfma_f32_16x16x32_bf16(bfr[n], af[m], acc[m][n], 0, 0, 0);
        }
        __builtin_amdgcn_sched_barrier(0);
        __builtin_amdgcn_s_barrier();   // all reads of buf[cur] done before restage
    }

    // epilogue: C^T frag -> row = row0+wr+m*16+l15, cols = col0+wc+n*16+kg*4 .. +3
    unsigned short* __restrict__ dstp = (col0 < 256) ? el16 : er16;
    const int ccbase = col0 & 255;
    #pragma unroll
    for (int m = 0; m < 4; ++m) {
        int row = row0 + wr + m*16 + l15;
        if (row >= N) continue;
        #pragma unroll
        for (int n = 0; n < 4; ++n) {
            int cw = wc + n*16 + kg*4;
            float4 b4 = *(const float4*)(biascat + col0 + cw);
            ushort4 o;
            o.x = f2bf(acc[m][n][0] + b4.x);
            o.y = f2bf(acc[m][n][1] + b4.y);
            o.z = f2bf(acc[m][n][2] + b4.z);
            o.w = f2bf(acc[m][n][3] + b4.w);
            *(ushort4*)(dstp + (size_t)row*D + ccbase + cw) = o;
        }
    }
}

// ---------------- CSR build ----------------
__global__ __launch_bounds__(256) void scan1_kernel(const int* __restrict__ deg,
                                                    int* __restrict__ incl,
                                                    int* __restrict__ bsum, int N){
    __shared__ int s[256];
    int i = blockIdx.x*256 + threadIdx.x;
    int v = (i < N) ? deg[i] : 0;
    s[threadIdx.x] = v;
    __syncthreads();
    #pragma unroll
    for (int off = 1; off < 256; off <<= 1){
        int t = (threadIdx.x >= off) ? s[threadIdx.x - off] : 0;
        __syncthreads();
        s[threadIdx.x] += t;
        __syncthreads();
    }
    if (i < N) incl[i] = s[threadIdx.x];
    if (threadIdx.x == 255) bsum[blockIdx.x] = s[255];
}

// scan3 with inlined scan2: each block computes its own exclusive prefix of bsum
// (nb <= ~400 ints: one wave grid-strides + shuffle-reduce; trivial cost)
__global__ __launch_bounds__(256) void scan23_kernel(const int* __restrict__ deg,
                                                     const int* __restrict__ incl,
                                                     const int* __restrict__ bsum,
                                                     int* __restrict__ rowstart,
                                                     int* __restrict__ cursor, int N){
    __shared__ int sbase;
    int b = blockIdx.x;
    if (threadIdx.x < 64){
        int acc = 0;
        for (int i = threadIdx.x; i < b; i += 64) acc += bsum[i];
        #pragma unroll
        for (int off = 32; off > 0; off >>= 1) acc += __shfl_xor(acc, off, 64);
        if (threadIdx.x == 0) sbase = acc;
    }
    __syncthreads();
    int i = b*256 + threadIdx.x;
    if (i < N){
        int st = incl[i] - deg[i] + sbase;
        rowstart[i] = st;
        cursor[i]   = st;
    }
}

// write SOURCE NODE id directly into CSR slot (no eid indirection)
__global__ void scatter_kernel(const int* __restrict__ dst, const int* __restrict__ src,
                               int* __restrict__ cursor, int* __restrict__ srcs, int E){
    int e = blockIdx.x*blockDim.x + threadIdx.x;
    if (e < E){
        int pos = atomicAdd(&cursor[dst[e]], 1);
        srcs[pos] = src[e];
    }
}

// ---------------- fused score + online-softmax + aggregate (one wave / dst) -------
// r13-proven version: 4-edge batches, 4 gathers in flight, 4 reduce chains.
__global__ __launch_bounds__(256) void gat_node_kernel(
    const unsigned short* __restrict__ el16, const unsigned short* __restrict__ er16,
    const float* __restrict__ attn, const int* __restrict__ srcs,
    const int* __restrict__ rowstart, const int* __restrict__ degv,
    float* __restrict__ out, int N)
{
    int node = blockIdx.x*4 + (threadIdx.x >> 6);
    if (node >= N) return;
    int lane = threadIdx.x & 63;
    float4 o = make_float4(0.f,0.f,0.f,0.f);
    int deg = degv[node];
    float* op = out + (size_t)node*D + lane*4;
    if (deg == 0){ *(float4*)op = o; return; }

    ushort4 rv = *(const ushort4*)(er16 + (size_t)node*D + lane*4);
    float4 r4 = make_float4(b2f(rv.x), b2f(rv.y), b2f(rv.z), b2f(rv.w));
    float4 a4 = *(const float4*)(attn + lane*4);
    int start = rowstart[node];

    float m = -INFINITY, ssum = 0.f;
    for (int base = 0; base < deg; base += 4){
        int cnt = deg - base; if (cnt > 4) cnt = 4;
        float4 l[4]; float p[4];
        #pragma unroll
        for (int j = 0; j < 4; ++j){
            int k = base + j; if (k >= deg) k = deg - 1;
            int sn = srcs[start + k];
            ushort4 lv = *(const ushort4*)(el16 + (size_t)sn*D + lane*4);
            l[j] = make_float4(b2f(lv.x), b2f(lv.y), b2f(lv.z), b2f(lv.w));
        }
        #pragma unroll
        for (int j = 0; j < 4; ++j){
            float x, pp = 0.f;
            x = l[j].x + r4.x; pp += (x > 0.f ? x : NEG*x) * a4.x;
            x = l[j].y + r4.y; pp += (x > 0.f ? x : NEG*x) * a4.y;
            x = l[j].z + r4.z; pp += (x > 0.f ? x : NEG*x) * a4.z;
            x = l[j].w + r4.w; pp += (x > 0.f ? x : NEG*x) * a4.w;
            p[j] = pp;
        }
        #pragma unroll
        for (int off = 32; off > 0; off >>= 1){
            #pragma unroll
            for (int j = 0; j < 4; ++j) p[j] += __shfl_xor(p[j], off, 64);
        }
        #pragma unroll
        for (int j = 0; j < 4; ++j){
            if (j >= cnt) break;
            float newm  = fmaxf(m, p[j]);
            float scale = __expf(m - newm);
            float w     = __expf(p[j] - newm);
            ssum = ssum*scale + w;
            o.x = o.x*scale + w*l[j].x;
            o.y = o.y*scale + w*l[j].y;
            o.z = o.z*scale + w*l[j].z;
            o.w = o.w*scale + w*l[j].w;
            m = newm;
        }
    }
    float inv = 1.f/ssum;
    o.x *= inv; o.y *= inv; o.z *= inv; o.w *= inv;
    *(float4*)op = o;
}

extern "C" void kernel_launch(void* const* d_in, const int* in_sizes, int n_in,
                              void* d_out, int out_size, void* d_ws, size_t ws_size,
                              hipStream_t stream)
{
    const float* feat = (const float*)d_in[0];
    const float* Wsrc = (const float*)d_in[1];
    const float* bsrc = (const float*)d_in[2];
    const float* Wdst = (const float*)d_in[3];
    const float* bdst = (const float*)d_in[4];
    const float* attn = (const float*)d_in[5];
    const int*   src  = (const int*)d_in[6];
    const int*   dst  = (const int*)d_in[7];
    const int N = in_sizes[0] / D;
    const int E = in_sizes[6];
    const int NPAD = ((N + 1023)/1024)*1024;   // panels (NPAD/128) divisible by 8
    const int NP = NPAD / 128;
    float* out = (float*)d_out;

    // ws: el16[N*D] er16[N*D] | deg incl rowstart cursor (N ints) | bsum[512] | srcs[E]
    //     | WT[512*256] | biascat[512 f32] | featb[NPAD*256]
    unsigned short* el16 = (unsigned short*)d_ws;
    unsigned short* er16 = el16 + (size_t)N*D;
    int* deg      = (int*)(er16 + (size_t)N*D);
    int* incl     = deg + N;
    int* rowstart = incl + N;
    int* cursor   = rowstart + N;
    int* bsum     = cursor + N;
    int* srcs     = bsum + 512;
    unsigned short* WT = (unsigned short*)(srcs + E);
    float* biascat = (float*)(WT + (size_t)512*D);
    unsigned short* featb = (unsigned short*)(biascat + 512);

    const int nb = (N + 255)/256;
    const int CB = (E + 255)/256;

    hipMemsetAsync(deg, 0, (size_t)N*sizeof(int), stream);

    prep_all_kernel<<<64 + CB + 4096, 256, 0, stream>>>(
        Wsrc, Wdst, bsrc, bdst, WT, biascat, feat, featb, N, NPAD, dst, deg, E, CB);

    proj_mfma_kernel<<<4*NP, 256, 0, stream>>>(featb, WT, biascat, el16, er16, N);

    scan1_kernel<<<nb, 256, 0, stream>>>(deg, incl, bsum, N);
    scan23_kernel<<<nb, 256, 0, stream>>>(deg, incl, bsum, rowstart, cursor, N);
    scatter_kernel<<<(E + 255)/256, 256, 0, stream>>>(dst, src, cursor, srcs, E);

    gat_node_kernel<<<(N + 3)/4, 256, 0, stream>>>(el16, er16, attn, srcs,
                                                   rowstart, deg, out, N);
}